// Round 1
// baseline (2959.268 us; speedup 1.0000x reference)
//
#include <hip/hip_runtime.h>

// Problem constants (from reference): B=2, T=2048, D_IN=D_OUT=512, H=8, DK=64
constexpr int B_   = 2;
constexpr int T_   = 2048;
constexpr int DIN  = 512;
constexpr int DOUT = 512;
constexpr int H_   = 8;
constexpr int DK_  = 64;
constexpr int QB   = 8;     // query rows per attention block

// ---------------------------------------------------------------------------
// Generic fp32 GEMM: out = X @ W^T + bias
//   X: [M=4096, K=512] row-major, W: [N=512, K=512] row-major, bias: [N]
//   head_layout=1: store at [B,H,T,DK] (for attention); 0: flat [M,N]
// 64x64 block tile, BK=16, 256 threads, 4x4 register tile per thread.
// ---------------------------------------------------------------------------
__global__ __launch_bounds__(256) void gemm_kernel(
    const float* __restrict__ X, const float* __restrict__ W,
    const float* __restrict__ bias, float* __restrict__ out, int head_layout)
{
    constexpr int K = DIN;
    constexpr int N = DOUT;
    __shared__ float Xs[64][20];   // padded to 20 floats: 16B-aligned rows, ~2-way banks
    __shared__ float Ws[64][20];

    const int tid = threadIdx.x;
    const int tx  = tid & 15;       // 0..15 -> output col group
    const int ty  = tid >> 4;       // 0..15 -> output row group
    const int m0  = blockIdx.y * 64;
    const int n0  = blockIdx.x * 64;
    const int lm  = tid >> 2;       // 0..63 loading row
    const int lk  = (tid & 3) * 4;  // 0,4,8,12 loading col (float4)

    float acc[4][4] = {};

    for (int k0 = 0; k0 < K; k0 += 16) {
        float4 xv4 = *(const float4*)&X[(size_t)(m0 + lm) * K + k0 + lk];
        float4 wv4 = *(const float4*)&W[(size_t)(n0 + lm) * K + k0 + lk];
        *(float4*)&Xs[lm][lk] = xv4;
        *(float4*)&Ws[lm][lk] = wv4;
        __syncthreads();
#pragma unroll
        for (int kk = 0; kk < 16; ++kk) {
            float xr[4], wr[4];
#pragma unroll
            for (int i = 0; i < 4; ++i) {
                xr[i] = Xs[ty + 16 * i][kk];
                wr[i] = Ws[tx + 16 * i][kk];
            }
#pragma unroll
            for (int i = 0; i < 4; ++i)
#pragma unroll
                for (int j = 0; j < 4; ++j)
                    acc[i][j] = fmaf(xr[i], wr[j], acc[i][j]);
        }
        __syncthreads();
    }

#pragma unroll
    for (int i = 0; i < 4; ++i) {
        const int m = m0 + ty + 16 * i;
#pragma unroll
        for (int j = 0; j < 4; ++j) {
            const int n = n0 + tx + 16 * j;
            const float v = acc[i][j] + bias[n];
            if (head_layout) {
                const int bb = m >> 11;        // m / T
                const int t  = m & (T_ - 1);
                const int hh = n >> 6;         // n / DK
                const int d  = n & (DK_ - 1);
                out[(((size_t)bb * H_ + hh) * T_ + t) * DK_ + d] = v;
            } else {
                out[(size_t)m * N + n] = v;
            }
        }
    }
}

// ---------------------------------------------------------------------------
// Attention: per block, QB=8 query rows of one (b,h).
//   scores[8][2048] live in LDS (64 KB). Softmax with max-subtraction, then
//   sparsify: keep p > row-mean. Since sum(p)=1 over T entries, mean = 1/T,
//   i.e. keep exp(s-m) > l/T. Then PV and write concat[B,T,DOUT].
// ---------------------------------------------------------------------------
__global__ __launch_bounds__(256) void attn_kernel(
    const float* __restrict__ Qh, const float* __restrict__ Kh,
    const float* __restrict__ Vh, float* __restrict__ concat)
{
    __shared__ float s_s[QB][T_];     // 64 KB
    __shared__ float s_q[QB][DK_];    // 2 KB

    const int bh = blockIdx.y;        // b*H + h
    const int b  = bh / H_;
    const int h  = bh % H_;
    const int q0 = blockIdx.x * QB;

    const float* Qp = Qh + ((size_t)bh * T_ + q0) * DK_;
    const float* Kp = Kh + (size_t)bh * T_ * DK_;
    const float* Vp = Vh + (size_t)bh * T_ * DK_;

    const int tid = threadIdx.x;

    // load Q tile (contiguous, coalesced)
    for (int i = tid; i < QB * DK_; i += 256)
        s_q[i >> 6][i & (DK_ - 1)] = Qp[i];
    __syncthreads();

    // ---- phase 1: scores. 8 row-groups x 32 lanes.
    const int qi   = tid >> 5;
    const int lane = tid & 31;
    for (int j = lane; j < T_; j += 32) {
        const float4* kr = (const float4*)(Kp + (size_t)j * DK_);
        float a = 0.f;
#pragma unroll
        for (int c = 0; c < DK_ / 4; ++c) {
            float4 k4 = kr[c];
            a = fmaf(k4.x, s_q[qi][4 * c + 0], a);
            a = fmaf(k4.y, s_q[qi][4 * c + 1], a);
            a = fmaf(k4.z, s_q[qi][4 * c + 2], a);
            a = fmaf(k4.w, s_q[qi][4 * c + 3], a);
        }
        s_s[qi][j] = a;
    }
    // each thread wrote exactly the j's it will reduce below -> no sync needed

    // ---- phase 2: row max, exp, sum, threshold (half-wave = 32-lane groups)
    float m = -1e30f;
    for (int j = lane; j < T_; j += 32) m = fmaxf(m, s_s[qi][j]);
#pragma unroll
    for (int off = 16; off >= 1; off >>= 1) m = fmaxf(m, __shfl_xor(m, off, 32));

    float sum = 0.f;
    for (int j = lane; j < T_; j += 32) {
        float e = __expf(s_s[qi][j] - m);
        s_s[qi][j] = e;
        sum += e;
    }
#pragma unroll
    for (int off = 16; off >= 1; off >>= 1) sum += __shfl_xor(sum, off, 32);

    const float thr = sum / (float)T_;   // e > thr  <=>  p > 1/T = row mean
    const float inv = 1.f / sum;
    for (int j = lane; j < T_; j += 32) {
        float e = s_s[qi][j];
        s_s[qi][j] = (e > thr) ? e * inv : 0.f;
    }
    __syncthreads();

    // ---- phase 3: PV. 4 groups x 64 dims; each thread does rows g and g+4.
    const int dg = tid & 63;
    const int g  = tid >> 6;
    float acc0 = 0.f, acc1 = 0.f;
#pragma unroll 4
    for (int j = 0; j < T_; ++j) {
        const float v = Vp[(size_t)j * DK_ + dg];   // coalesced across 64 lanes
        acc0 = fmaf(s_s[g][j], v, acc0);            // LDS broadcast (uniform in wave)
        acc1 = fmaf(s_s[g + 4][j], v, acc1);
    }
    concat[((size_t)b * T_ + q0 + g)     * DOUT + h * DK_ + dg] = acc0;
    concat[((size_t)b * T_ + q0 + g + 4) * DOUT + h * DK_ + dg] = acc1;
}

// ---------------------------------------------------------------------------
extern "C" void kernel_launch(void* const* d_in, const int* in_sizes, int n_in,
                              void* d_out, int out_size, void* d_ws, size_t ws_size,
                              hipStream_t stream)
{
    const float* q  = (const float*)d_in[0];
    const float* k  = (const float*)d_in[1];
    const float* v  = (const float*)d_in[2];
    const float* Wq = (const float*)d_in[3];
    const float* bq = (const float*)d_in[4];
    const float* Wk = (const float*)d_in[5];
    const float* bk = (const float*)d_in[6];
    const float* Wv = (const float*)d_in[7];
    const float* bv = (const float*)d_in[8];
    const float* Wo = (const float*)d_in[9];
    const float* bo = (const float*)d_in[10];
    float* out = (float*)d_out;

    const size_t per = (size_t)B_ * H_ * T_ * DK_;   // 2M floats
    float* Qh     = (float*)d_ws;
    float* Kh     = Qh + per;
    float* Vh     = Kh + per;
    float* concat = Vh + per;

    const dim3 gemm_grid(DOUT / 64, (B_ * T_) / 64);   // (8, 64)
    gemm_kernel<<<gemm_grid, 256, 0, stream>>>(q, Wq, bq, Qh, 1);
    gemm_kernel<<<gemm_grid, 256, 0, stream>>>(k, Wk, bk, Kh, 1);
    gemm_kernel<<<gemm_grid, 256, 0, stream>>>(v, Wv, bv, Vh, 1);

    const dim3 attn_grid(T_ / QB, B_ * H_);            // (256, 16)
    attn_kernel<<<attn_grid, 256, 0, stream>>>(Qh, Kh, Vh, concat);

    gemm_kernel<<<gemm_grid, 256, 0, stream>>>(concat, Wo, bo, out, 0);
}

// Round 2
// 296.959 us; speedup vs baseline: 9.9652x; 9.9652x over previous
//
#include <hip/hip_runtime.h>

// B=2, T=2048, D_IN=D_OUT=512, H=8, DK=64
constexpr int B_   = 2;
constexpr int T_   = 2048;
constexpr int DIN  = 512;
constexpr int DOUT = 512;
constexpr int H_   = 8;
constexpr int DK_  = 64;

typedef float    f32x16  __attribute__((ext_vector_type(16)));
typedef short    short8v __attribute__((ext_vector_type(8)));
typedef __bf16   bf16x8  __attribute__((ext_vector_type(8)));

__device__ inline f32x16 mfma3216(short8v a, short8v b, f32x16 c) {
    return __builtin_amdgcn_mfma_f32_32x32x16_bf16(
        __builtin_bit_cast(bf16x8, a), __builtin_bit_cast(bf16x8, b), c, 0, 0, 0);
}

__device__ inline unsigned bf16rne(float f) {
    union { float f; unsigned u; } x{f};
    return (x.u + 0x7fffu + ((x.u >> 16) & 1u)) >> 16;
}
__device__ inline unsigned pk2(float lo, float hi) {
    return bf16rne(lo) | (bf16rne(hi) << 16);
}

// ---------------------------------------------------------------------------
// fp32 GEMM: out = X @ W^T + bias.  X:[M=4096,K=512], W:[N=512,K=512]
// mode 0: f32 flat [M,N]; mode 1: bf16 [B,H,T,DK]; mode 2: bf16 [B,H,DK,T]
// ---------------------------------------------------------------------------
__global__ __launch_bounds__(256) void gemm_kernel(
    const float* __restrict__ X, const float* __restrict__ W,
    const float* __restrict__ bias, float* __restrict__ outf,
    unsigned short* __restrict__ outb, int mode)
{
    constexpr int K = DIN;
    constexpr int N = DOUT;
    __shared__ float Xs[64][20];
    __shared__ float Ws[64][20];

    const int tid = threadIdx.x;
    const int tx  = tid & 15;
    const int ty  = tid >> 4;
    const int m0  = blockIdx.y * 64;
    const int n0  = blockIdx.x * 64;
    const int lm  = tid >> 2;
    const int lk  = (tid & 3) * 4;

    float acc[4][4] = {};

    for (int k0 = 0; k0 < K; k0 += 16) {
        float4 xv4 = *(const float4*)&X[(size_t)(m0 + lm) * K + k0 + lk];
        float4 wv4 = *(const float4*)&W[(size_t)(n0 + lm) * K + k0 + lk];
        *(float4*)&Xs[lm][lk] = xv4;
        *(float4*)&Ws[lm][lk] = wv4;
        __syncthreads();
#pragma unroll
        for (int kk = 0; kk < 16; ++kk) {
            float xr[4], wr[4];
#pragma unroll
            for (int i = 0; i < 4; ++i) {
                xr[i] = Xs[ty + 16 * i][kk];
                wr[i] = Ws[tx + 16 * i][kk];
            }
#pragma unroll
            for (int i = 0; i < 4; ++i)
#pragma unroll
                for (int j = 0; j < 4; ++j)
                    acc[i][j] = fmaf(xr[i], wr[j], acc[i][j]);
        }
        __syncthreads();
    }

#pragma unroll
    for (int i = 0; i < 4; ++i) {
        const int m = m0 + ty + 16 * i;
#pragma unroll
        for (int j = 0; j < 4; ++j) {
            const int n = n0 + tx + 16 * j;
            const float v = acc[i][j] + bias[n];
            if (mode == 0) {
                outf[(size_t)m * N + n] = v;
            } else {
                const int bb = m >> 11, t = m & (T_ - 1);
                const int hh = n >> 6,  d = n & (DK_ - 1);
                const unsigned short bv = (unsigned short)bf16rne(v);
                if (mode == 1)
                    outb[(((size_t)bb * H_ + hh) * T_ + t) * DK_ + d] = bv;
                else
                    outb[(((size_t)bb * H_ + hh) * DK_ + d) * T_ + t] = bv;
            }
        }
    }
}

// ---------------------------------------------------------------------------
// MFMA two-pass attention. Block = 256 thr = 4 waves.
// Block owns 64 q-rows of one (b,h): 2 q-subtiles x 2 key-halves.
// Wave: 32 q-rows, 1024 keys. Swapped QK^T (S^T = mfma(K,Q)).
// Pass 1: l = sum exp(s). Pass 2: e>l/T mask, PV accumulate, LDS combine.
// ---------------------------------------------------------------------------
__global__ __launch_bounds__(256) void attn_kernel(
    const unsigned short* __restrict__ Qh, const unsigned short* __restrict__ Kh,
    const unsigned short* __restrict__ Vt, float* __restrict__ concat)
{
    __shared__ float lds_l[2][2][32];
    __shared__ float lds_out[2][32][64];

    // XCD swizzle: 512 blocks, XCD x owns bh {2x, 2x+1} (L2-resident K/V)
    const int bid  = blockIdx.x;
    const int xcd  = bid & 7;
    const int j    = bid >> 3;            // 0..63
    const int bh   = 2 * xcd + (j >> 5);
    const int qt   = j & 31;

    const int tid    = threadIdx.x;
    const int wv     = tid >> 6;
    const int qsub   = wv >> 1;
    const int khalf  = wv & 1;
    const int l      = tid & 63;
    const int lane31 = l & 31;
    const int hi     = l >> 5;

    const int q0 = qt * 64 + qsub * 32;
    const unsigned short* Qb  = Qh + ((size_t)bh * T_ + q0) * DK_;
    const unsigned short* Kb0 = Kh + (size_t)bh * T_ * DK_;
    const unsigned short* Vb0 = Vt + (size_t)bh * DK_ * T_;

    // Q B-fragments: col = lane31 (query), k = d = c*16 + hi*8 + {0..7}
    short8v qf[4];
#pragma unroll
    for (int c = 0; c < 4; ++c)
        qf[c] = *(const short8v*)(Qb + (size_t)lane31 * DK_ + c * 16 + hi * 8);

    const int kstart = khalf * 1024;

    // ---- pass 1: denominators
    float lsum = 0.f;
    for (int kt = 0; kt < 32; ++kt) {
        const unsigned short* Kb = Kb0 + (size_t)(kstart + kt * 32) * DK_;
        short8v kf[4];
#pragma unroll
        for (int c = 0; c < 4; ++c)
            kf[c] = *(const short8v*)(Kb + (size_t)lane31 * DK_ + c * 16 + hi * 8);
        f32x16 acc = {};
#pragma unroll
        for (int c = 0; c < 4; ++c)
            acc = mfma3216(kf[c], qf[c], acc);
#pragma unroll
        for (int r = 0; r < 16; ++r)
            lsum += __expf(acc[r]);
    }
    lsum += __shfl_xor(lsum, 32);
    if (l < 32) lds_l[qsub][khalf][l] = lsum;
    __syncthreads();
    const float ltot = lsum + lds_l[qsub][khalf ^ 1][lane31];
    const float thr  = ltot * (1.0f / 2048.0f);   // e > thr  <=>  p > row mean
    const float inv  = 1.0f / ltot;

    // ---- pass 2: masked PV
    f32x16 o0 = {}, o1 = {};
    for (int kt = 0; kt < 32; ++kt) {
        const int kbase = kstart + kt * 32;
        const unsigned short* Kb = Kb0 + (size_t)kbase * DK_;
        short8v kf[4];
#pragma unroll
        for (int c = 0; c < 4; ++c)
            kf[c] = *(const short8v*)(Kb + (size_t)lane31 * DK_ + c * 16 + hi * 8);
        f32x16 acc = {};
#pragma unroll
        for (int c = 0; c < 4; ++c)
            acc = mfma3216(kf[c], qf[c], acc);

        float p[16];
#pragma unroll
        for (int r = 0; r < 16; ++r) {
            const float e = __expf(acc[r]);
            p[r] = (e > thr) ? e : 0.f;
        }

        // repack S^T (key split {0-3,8-11,..}+4hi) -> PV A-frag (keys 8hi..8hi+7)
        short8v pa[2];
#pragma unroll
        for (int h = 0; h < 2; ++h) {
            const unsigned a  = pk2(p[8 * h + 0], p[8 * h + 1]);
            const unsigned b2 = pk2(p[8 * h + 2], p[8 * h + 3]);
            const unsigned c2 = pk2(p[8 * h + 4], p[8 * h + 5]);
            const unsigned d2 = pk2(p[8 * h + 6], p[8 * h + 7]);
            const unsigned sa = (unsigned)__shfl_xor((int)a,  32);
            const unsigned sb = (unsigned)__shfl_xor((int)b2, 32);
            const unsigned sc = (unsigned)__shfl_xor((int)c2, 32);
            const unsigned sd = (unsigned)__shfl_xor((int)d2, 32);
            union { unsigned w[4]; short8v v; } u;
            u.w[0] = hi ? sc : a;
            u.w[1] = hi ? sd : b2;
            u.w[2] = hi ? c2 : sa;
            u.w[3] = hi ? d2 : sb;
            pa[h] = u.v;
        }

#pragma unroll
        for (int h = 0; h < 2; ++h) {
            const unsigned short* Vb = Vb0 + (size_t)lane31 * T_ + kbase + h * 16 + hi * 8;
            short8v vf0 = *(const short8v*)(Vb);
            short8v vf1 = *(const short8v*)(Vb + (size_t)32 * T_);
            o0 = mfma3216(pa[h], vf0, o0);
            o1 = mfma3216(pa[h], vf1, o1);
        }
    }

    // ---- combine key-halves via LDS, scale by 1/l, store
    if (khalf) {
#pragma unroll
        for (int r = 0; r < 16; ++r) {
            const int row = (r & 3) + 8 * (r >> 2) + 4 * hi;
            lds_out[qsub][row][lane31]      = o0[r];
            lds_out[qsub][row][32 + lane31] = o1[r];
        }
    }
    __syncthreads();
    if (!khalf) {
        const int b = bh >> 3, h = bh & 7;
        float* Cb = concat + ((size_t)b * T_ + q0) * DOUT + h * DK_;
#pragma unroll
        for (int r = 0; r < 16; ++r) {
            const int row = (r & 3) + 8 * (r >> 2) + 4 * hi;
            const float iv = __shfl(inv, row);
            Cb[(size_t)row * DOUT + lane31]      = (o0[r] + lds_out[qsub][row][lane31]) * iv;
            Cb[(size_t)row * DOUT + 32 + lane31] = (o1[r] + lds_out[qsub][row][32 + lane31]) * iv;
        }
    }
}

// ---------------------------------------------------------------------------
extern "C" void kernel_launch(void* const* d_in, const int* in_sizes, int n_in,
                              void* d_out, int out_size, void* d_ws, size_t ws_size,
                              hipStream_t stream)
{
    const float* q  = (const float*)d_in[0];
    const float* k  = (const float*)d_in[1];
    const float* v  = (const float*)d_in[2];
    const float* Wq = (const float*)d_in[3];
    const float* bq = (const float*)d_in[4];
    const float* Wk = (const float*)d_in[5];
    const float* bk = (const float*)d_in[6];
    const float* Wv = (const float*)d_in[7];
    const float* bv = (const float*)d_in[8];
    const float* Wo = (const float*)d_in[9];
    const float* bo = (const float*)d_in[10];
    float* out = (float*)d_out;

    const size_t per = (size_t)B_ * H_ * T_ * DK_;       // 2M elements
    unsigned short* Qh = (unsigned short*)d_ws;          // 4 MB
    unsigned short* Kh = Qh + per;                       // 4 MB
    unsigned short* Vt = Kh + per;                       // 4 MB
    float* concat = (float*)(Vt + per);                  // 8 MB

    const dim3 gemm_grid(DOUT / 64, (B_ * T_) / 64);     // (8, 64)
    gemm_kernel<<<gemm_grid, 256, 0, stream>>>(q, Wq, bq, nullptr, Qh, 1);
    gemm_kernel<<<gemm_grid, 256, 0, stream>>>(k, Wk, bk, nullptr, Kh, 1);
    gemm_kernel<<<gemm_grid, 256, 0, stream>>>(v, Wv, bv, nullptr, Vt, 2);

    attn_kernel<<<dim3(512), 256, 0, stream>>>(Qh, Kh, Vt, concat);

    gemm_kernel<<<gemm_grid, 256, 0, stream>>>(concat, Wo, bo, out, nullptr, 0);
}

// Round 3
// 142.238 us; speedup vs baseline: 20.8051x; 2.0878x over previous
//
#include <hip/hip_runtime.h>

// B=2, T=2048, D_IN=D_OUT=512, H=8, DK=64
constexpr int B_   = 2;
constexpr int T_   = 2048;
constexpr int DIN  = 512;
constexpr int DOUT = 512;
constexpr int H_   = 8;
constexpr int DK_  = 64;

typedef float    f32x16  __attribute__((ext_vector_type(16)));
typedef short    short8v __attribute__((ext_vector_type(8)));
typedef __bf16   bf16x8  __attribute__((ext_vector_type(8)));

__device__ inline f32x16 mfma3216(short8v a, short8v b, f32x16 c) {
    return __builtin_amdgcn_mfma_f32_32x32x16_bf16(
        __builtin_bit_cast(bf16x8, a), __builtin_bit_cast(bf16x8, b), c, 0, 0, 0);
}

__device__ inline unsigned short bf16c(float f) {
    return __builtin_bit_cast(unsigned short, (__bf16)f);
}
__device__ inline float bf2f(unsigned short u) {
    return (float)__builtin_bit_cast(__bf16, u);
}
__device__ inline unsigned pk2(float lo, float hi) {
    return (unsigned)bf16c(lo) | ((unsigned)bf16c(hi) << 16);
}

// ---------------------------------------------------------------------------
// Conversion: q,k,v f32 -> bf16; Wq,Wk,Wv,Wo f32 -> bf16 hi + bf16 lo (split).
// 1792 blocks x 256 thr, 4096 elems/block.
// Blocks [0,512)=q, [512,1024)=k, [1024,1536)=v, then 64 each for Wq,Wk,Wv,Wo.
// ---------------------------------------------------------------------------
__global__ __launch_bounds__(256) void convert_kernel(
    const float* __restrict__ q, const float* __restrict__ k, const float* __restrict__ v,
    const float* __restrict__ Wq, const float* __restrict__ Wk,
    const float* __restrict__ Wv, const float* __restrict__ Wo,
    unsigned short* __restrict__ qb, unsigned short* __restrict__ kb,
    unsigned short* __restrict__ vb,
    unsigned short* __restrict__ Wh, unsigned short* __restrict__ Wl)
{
    const int b = blockIdx.x, t = threadIdx.x;
    const float* src;
    unsigned short* hi;
    unsigned short* lo = nullptr;
    size_t off;
    if (b < 1536) {
        const int which = b >> 9;
        src = which == 0 ? q : (which == 1 ? k : v);
        hi  = which == 0 ? qb : (which == 1 ? kb : vb);
        off = (size_t)(b & 511) * 4096;
    } else {
        const int wb = b - 1536;
        const int wi = wb >> 6;
        src = wi == 0 ? Wq : (wi == 1 ? Wk : (wi == 2 ? Wv : Wo));
        hi  = Wh + (size_t)wi * 262144;
        lo  = Wl + (size_t)wi * 262144;
        off = (size_t)(wb & 63) * 4096;
    }
#pragma unroll
    for (int c = 0; c < 4; ++c) {
        const size_t idx = off + (size_t)c * 1024 + (size_t)t * 4;
        const float4 x = *(const float4*)&src[idx];
        ushort4 h;
        h.x = bf16c(x.x); h.y = bf16c(x.y); h.z = bf16c(x.z); h.w = bf16c(x.w);
        *(ushort4*)&hi[idx] = h;
        if (lo) {
            ushort4 l2;
            l2.x = bf16c(x.x - bf2f(h.x));
            l2.y = bf16c(x.y - bf2f(h.y));
            l2.z = bf16c(x.z - bf2f(h.z));
            l2.w = bf16c(x.w - bf2f(h.w));
            *(ushort4*)&lo[idx] = l2;
        }
    }
}

// ---------------------------------------------------------------------------
// MFMA GEMM: out = A @ (Wh+Wl)^T + bias.  A:[4096,512] bf16, Wh/Wl:[512,512] bf16.
// BM=128, BN=64, BK=32, 256 thr = 4 waves (2x2), wave tile 64x32.
// LDS XOR-swizzle: 16B chunk pos ^= (row>>1)&3 (4-way volume-min b128 reads).
// MODE 0: f32 flat [M,N]; 1: bf16 [B,H,T,DK]; 2: bf16 [B,H,DK,T]
// ---------------------------------------------------------------------------
template<int MODE>
__device__ inline void gemm_body(
    const unsigned short* __restrict__ A, const unsigned short* __restrict__ Bh,
    const unsigned short* __restrict__ Bl, const float* __restrict__ bias,
    unsigned short* __restrict__ outb, float* __restrict__ outf)
{
    __shared__ unsigned short As[128 * 32];
    __shared__ unsigned short Bsh[64 * 32];
    __shared__ unsigned short Bsl[64 * 32];

    const int tid = threadIdx.x;
    const int m0 = blockIdx.y * 128, n0 = blockIdx.x * 64;
    const int lane = tid & 63, lane31 = lane & 31, hi8 = lane >> 5;
    const int wv = tid >> 6, wm = wv >> 1, wn = wv & 1;

    f32x16 acc0 = {}, acc1 = {};

    for (int kb = 0; kb < 16; ++kb) {
        const int k0 = kb * 32;
        // ---- stage (reg -> swizzled ds_write)
#pragma unroll
        for (int i = 0; i < 2; ++i) {
            const int c = tid + i * 256;          // 512 chunks: 128 rows x 4
            const int r = c >> 2, pos = c & 3;
            const short8v av = *(const short8v*)&A[(size_t)(m0 + r) * DIN + k0 + pos * 8];
            const int sw = pos ^ ((r >> 1) & 3);
            *(short8v*)((char*)As + r * 64 + sw * 16) = av;
        }
        {
            const int c = tid;                    // 256 chunks: 64 rows x 4
            const int r = c >> 2, pos = c & 3;
            const short8v bh = *(const short8v*)&Bh[(size_t)(n0 + r) * DIN + k0 + pos * 8];
            const short8v bl = *(const short8v*)&Bl[(size_t)(n0 + r) * DIN + k0 + pos * 8];
            const int sw = pos ^ ((r >> 1) & 3);
            *(short8v*)((char*)Bsh + r * 64 + sw * 16) = bh;
            *(short8v*)((char*)Bsl + r * 64 + sw * 16) = bl;
        }
        __syncthreads();
        // ---- compute 2 k-steps of 16
#pragma unroll
        for (int ks = 0; ks < 2; ++ks) {
            const int pos = ks * 2 + hi8;
            short8v a0, a1, bhf, blf;
            { const int r = wm * 64 + lane31;
              a0 = *(const short8v*)((char*)As + r * 64 + ((pos ^ ((r >> 1) & 3)) << 4)); }
            { const int r = wm * 64 + 32 + lane31;
              a1 = *(const short8v*)((char*)As + r * 64 + ((pos ^ ((r >> 1) & 3)) << 4)); }
            { const int r = wn * 32 + lane31;
              bhf = *(const short8v*)((char*)Bsh + r * 64 + ((pos ^ ((r >> 1) & 3)) << 4));
              blf = *(const short8v*)((char*)Bsl + r * 64 + ((pos ^ ((r >> 1) & 3)) << 4)); }
            acc0 = mfma3216(a0, bhf, acc0);
            acc0 = mfma3216(a0, blf, acc0);
            acc1 = mfma3216(a1, bhf, acc1);
            acc1 = mfma3216(a1, blf, acc1);
        }
        __syncthreads();
    }

    // ---- epilogue
    const int n = n0 + wn * 32 + lane31;
    const float bn = bias[n];
#pragma unroll
    for (int r = 0; r < 16; ++r) {
        const int row = (r & 3) + 8 * (r >> 2) + 4 * hi8;
#pragma unroll
        for (int mt = 0; mt < 2; ++mt) {
            const int m = m0 + wm * 64 + mt * 32 + row;
            const float v = (mt ? acc1[r] : acc0[r]) + bn;
            if (MODE == 0) {
                outf[(size_t)m * DOUT + n] = v;
            } else {
                const int bb = m >> 11, t = m & (T_ - 1);
                const int hh = n >> 6,  d = n & (DK_ - 1);
                if (MODE == 1)
                    outb[(((size_t)bb * H_ + hh) * T_ + t) * DK_ + d] = bf16c(v);
                else
                    outb[(((size_t)bb * H_ + hh) * DK_ + d) * T_ + t] = bf16c(v);
            }
        }
    }
}

__global__ __launch_bounds__(256) void qkv_gemm(
    const unsigned short* __restrict__ qb, const unsigned short* __restrict__ kb,
    const unsigned short* __restrict__ vb,
    const unsigned short* __restrict__ Wh, const unsigned short* __restrict__ Wl,
    const float* __restrict__ bq, const float* __restrict__ bk, const float* __restrict__ bv,
    unsigned short* __restrict__ Qh, unsigned short* __restrict__ Kh,
    unsigned short* __restrict__ Vt)
{
    const int z = blockIdx.z;
    if (z == 0)      gemm_body<1>(qb, Wh,          Wl,          bq, Qh, nullptr);
    else if (z == 1) gemm_body<1>(kb, Wh + 262144, Wl + 262144, bk, Kh, nullptr);
    else             gemm_body<2>(vb, Wh + 524288, Wl + 524288, bv, Vt, nullptr);
}

__global__ __launch_bounds__(256) void out_gemm(
    const unsigned short* __restrict__ A,
    const unsigned short* __restrict__ Bh, const unsigned short* __restrict__ Bl,
    const float* __restrict__ bias, float* __restrict__ out)
{
    gemm_body<0>(A, Bh, Bl, bias, nullptr, out);
}

// ---------------------------------------------------------------------------
// MFMA two-pass attention. Block = 256 thr = 4 waves, 32 q-rows of one (b,h).
// Each wave owns a 512-key quarter (4-way key split -> 1024 blocks, 2x waves/CU).
// Pass 1: l = sum exp(s). Pass 2: e>l/T mask, PV accumulate, LDS combine.
// ---------------------------------------------------------------------------
__global__ __launch_bounds__(256) void attn_kernel(
    const unsigned short* __restrict__ Qh, const unsigned short* __restrict__ Kh,
    const unsigned short* __restrict__ Vt, unsigned short* __restrict__ concat)
{
    __shared__ float lds_l[4][32];
    __shared__ float lds_out[3][32][64];

    // XCD swizzle: 1024 blocks, XCD x owns bh {2x, 2x+1} (L2-resident K/V)
    const int bid = blockIdx.x;
    const int xcd = bid & 7;
    const int j   = bid >> 3;            // 0..127
    const int bh  = 2 * xcd + (j >> 6);
    const int qt  = j & 63;

    const int tid    = threadIdx.x;
    const int w      = tid >> 6;         // key quarter
    const int l      = tid & 63;
    const int lane31 = l & 31;
    const int hi     = l >> 5;

    const int q0 = qt * 32;
    const unsigned short* Qb  = Qh + ((size_t)bh * T_ + q0) * DK_;
    const unsigned short* Kb0 = Kh + (size_t)bh * T_ * DK_;
    const unsigned short* Vb0 = Vt + (size_t)bh * DK_ * T_;

    // Q B-fragments: col = lane31 (query), k = d = c*16 + hi*8 + {0..7}
    short8v qf[4];
#pragma unroll
    for (int c = 0; c < 4; ++c)
        qf[c] = *(const short8v*)(Qb + (size_t)lane31 * DK_ + c * 16 + hi * 8);

    const int kstart = w * 512;

    // ---- pass 1: denominators
    float lsum = 0.f;
    for (int kt = 0; kt < 16; ++kt) {
        const unsigned short* Kb = Kb0 + (size_t)(kstart + kt * 32) * DK_;
        short8v kf[4];
#pragma unroll
        for (int c = 0; c < 4; ++c)
            kf[c] = *(const short8v*)(Kb + (size_t)lane31 * DK_ + c * 16 + hi * 8);
        f32x16 acc = {};
#pragma unroll
        for (int c = 0; c < 4; ++c)
            acc = mfma3216(kf[c], qf[c], acc);
#pragma unroll
        for (int r = 0; r < 16; ++r)
            lsum += __expf(acc[r]);
    }
    lsum += __shfl_xor(lsum, 32);
    if (l < 32) lds_l[w][l] = lsum;
    __syncthreads();
    const float ltot = lds_l[0][lane31] + lds_l[1][lane31]
                     + lds_l[2][lane31] + lds_l[3][lane31];
    const float thr = ltot * (1.0f / 2048.0f);   // e > thr  <=>  p > row mean
    const float inv = 1.0f / ltot;

    // ---- pass 2: masked PV
    f32x16 o0 = {}, o1 = {};
    for (int kt = 0; kt < 16; ++kt) {
        const int kbase = kstart + kt * 32;
        const unsigned short* Kb = Kb0 + (size_t)kbase * DK_;
        short8v kf[4];
#pragma unroll
        for (int c = 0; c < 4; ++c)
            kf[c] = *(const short8v*)(Kb + (size_t)lane31 * DK_ + c * 16 + hi * 8);
        f32x16 acc = {};
#pragma unroll
        for (int c = 0; c < 4; ++c)
            acc = mfma3216(kf[c], qf[c], acc);

        float p[16];
#pragma unroll
        for (int r = 0; r < 16; ++r) {
            const float e = __expf(acc[r]);
            p[r] = (e > thr) ? e : 0.f;
        }

        // repack S^T (key split {0-3,8-11,..}+4hi) -> PV A-frag (keys 8hi..8hi+7)
        short8v pa[2];
#pragma unroll
        for (int h = 0; h < 2; ++h) {
            const unsigned a  = pk2(p[8 * h + 0], p[8 * h + 1]);
            const unsigned b2 = pk2(p[8 * h + 2], p[8 * h + 3]);
            const unsigned c2 = pk2(p[8 * h + 4], p[8 * h + 5]);
            const unsigned d2 = pk2(p[8 * h + 6], p[8 * h + 7]);
            const unsigned sa = (unsigned)__shfl_xor((int)a,  32);
            const unsigned sb = (unsigned)__shfl_xor((int)b2, 32);
            const unsigned sc = (unsigned)__shfl_xor((int)c2, 32);
            const unsigned sd = (unsigned)__shfl_xor((int)d2, 32);
            union { unsigned w2[4]; short8v v; } u;
            u.w2[0] = hi ? sc : a;
            u.w2[1] = hi ? sd : b2;
            u.w2[2] = hi ? c2 : sa;
            u.w2[3] = hi ? d2 : sb;
            pa[h] = u.v;
        }

#pragma unroll
        for (int h = 0; h < 2; ++h) {
            const unsigned short* Vb = Vb0 + (size_t)lane31 * T_ + kbase + h * 16 + hi * 8;
            short8v vf0 = *(const short8v*)(Vb);
            short8v vf1 = *(const short8v*)(Vb + (size_t)32 * T_);
            o0 = mfma3216(pa[h], vf0, o0);
            o1 = mfma3216(pa[h], vf1, o1);
        }
    }

    // ---- combine 4 key-quarters via LDS, scale by 1/l, store bf16
    if (w) {
#pragma unroll
        for (int r = 0; r < 16; ++r) {
            const int row = (r & 3) + 8 * (r >> 2) + 4 * hi;
            lds_out[w - 1][row][lane31]      = o0[r];
            lds_out[w - 1][row][32 + lane31] = o1[r];
        }
    }
    __syncthreads();
    if (!w) {
        const int b = bh >> 3, h = bh & 7;
        unsigned short* Cb = concat + ((size_t)b * T_ + q0) * DOUT + h * DK_;
#pragma unroll
        for (int r = 0; r < 16; ++r) {
            const int row = (r & 3) + 8 * (r >> 2) + 4 * hi;
            const float iv = __shfl(inv, row);
            const float v0 = o0[r] + lds_out[0][row][lane31]
                           + lds_out[1][row][lane31] + lds_out[2][row][lane31];
            const float v1 = o1[r] + lds_out[0][row][32 + lane31]
                           + lds_out[1][row][32 + lane31] + lds_out[2][row][32 + lane31];
            Cb[(size_t)row * DOUT + lane31]      = bf16c(v0 * iv);
            Cb[(size_t)row * DOUT + 32 + lane31] = bf16c(v1 * iv);
        }
    }
}

// ---------------------------------------------------------------------------
extern "C" void kernel_launch(void* const* d_in, const int* in_sizes, int n_in,
                              void* d_out, int out_size, void* d_ws, size_t ws_size,
                              hipStream_t stream)
{
    const float* q  = (const float*)d_in[0];
    const float* k  = (const float*)d_in[1];
    const float* v  = (const float*)d_in[2];
    const float* Wq = (const float*)d_in[3];
    const float* bq = (const float*)d_in[4];
    const float* Wk = (const float*)d_in[5];
    const float* bk = (const float*)d_in[6];
    const float* Wv = (const float*)d_in[7];
    const float* bv = (const float*)d_in[8];
    const float* Wo = (const float*)d_in[9];
    const float* bo = (const float*)d_in[10];
    float* out = (float*)d_out;

    constexpr size_t M2 = 2097152;  // 2M elements
    unsigned short* ws     = (unsigned short*)d_ws;
    unsigned short* qb     = ws;                 // 2M
    unsigned short* kb     = ws + 1 * M2;
    unsigned short* vb     = ws + 2 * M2;
    unsigned short* Qh     = ws + 3 * M2;
    unsigned short* Kh     = ws + 4 * M2;
    unsigned short* Vt     = ws + 5 * M2;
    unsigned short* concat = ws + 6 * M2;
    unsigned short* Wh     = ws + 7 * M2;        // 4 x 256K
    unsigned short* Wl     = ws + 7 * M2 + 1048576;

    convert_kernel<<<1792, 256, 0, stream>>>(q, k, v, Wq, Wk, Wv, Wo, qb, kb, vb, Wh, Wl);
    qkv_gemm<<<dim3(8, 32, 3), 256, 0, stream>>>(qb, kb, vb, Wh, Wl, bq, bk, bv, Qh, Kh, Vt);
    attn_kernel<<<dim3(1024), 256, 0, stream>>>(Qh, Kh, Vt, concat);
    out_gemm<<<dim3(8, 32), 256, 0, stream>>>(concat, Wh + 786432, Wl + 786432, bo, out);
}

// Round 6
// 103.431 us; speedup vs baseline: 28.6110x; 1.3752x over previous
//
#include <hip/hip_runtime.h>

// B=2, T=2048, D_IN=D_OUT=512, H=8, DK=64
constexpr int B_   = 2;
constexpr int T_   = 2048;
constexpr int DIN  = 512;
constexpr int DOUT = 512;
constexpr int H_   = 8;
constexpr int DK_  = 64;

typedef float    f32x16  __attribute__((ext_vector_type(16)));
typedef short    short8v __attribute__((ext_vector_type(8)));
typedef __bf16   bf16x8  __attribute__((ext_vector_type(8)));

__device__ inline f32x16 mfma3216(short8v a, short8v b, f32x16 c) {
    return __builtin_amdgcn_mfma_f32_32x32x16_bf16(
        __builtin_bit_cast(bf16x8, a), __builtin_bit_cast(bf16x8, b), c, 0, 0, 0);
}

__device__ inline unsigned short bf16c(float f) {
    return __builtin_bit_cast(unsigned short, (__bf16)f);
}
__device__ inline float bf2f(unsigned short u) {
    return (float)__builtin_bit_cast(__bf16, u);
}
__device__ inline unsigned pk2(float lo, float hi) {
    return (unsigned)bf16c(lo) | ((unsigned)bf16c(hi) << 16);
}

// ---------------------------------------------------------------------------
// Weight conversion only: Wq,Wk,Wv,Wo f32 -> bf16 hi + bf16 lo. 256 blocks.
// (Bit-identical per-element math to the previous convert kernel.)
// ---------------------------------------------------------------------------
__global__ __launch_bounds__(256) void wconvert_kernel(
    const float* __restrict__ Wq, const float* __restrict__ Wk,
    const float* __restrict__ Wv, const float* __restrict__ Wo,
    unsigned short* __restrict__ Wh, unsigned short* __restrict__ Wl)
{
    const int b = blockIdx.x, t = threadIdx.x;
    const int wi = b >> 6;
    const float* src = wi == 0 ? Wq : (wi == 1 ? Wk : (wi == 2 ? Wv : Wo));
    unsigned short* hi = Wh + (size_t)wi * 262144;
    unsigned short* lo = Wl + (size_t)wi * 262144;
    const size_t off = (size_t)(b & 63) * 4096;
#pragma unroll
    for (int c = 0; c < 4; ++c) {
        const size_t idx = off + (size_t)c * 1024 + (size_t)t * 4;
        const float4 x = *(const float4*)&src[idx];
        ushort4 h;
        h.x = bf16c(x.x); h.y = bf16c(x.y); h.z = bf16c(x.z); h.w = bf16c(x.w);
        *(ushort4*)&hi[idx] = h;
        ushort4 l2;
        l2.x = bf16c(x.x - bf2f(h.x));
        l2.y = bf16c(x.y - bf2f(h.y));
        l2.z = bf16c(x.z - bf2f(h.z));
        l2.w = bf16c(x.w - bf2f(h.w));
        *(ushort4*)&lo[idx] = l2;
    }
}

// ---------------------------------------------------------------------------
// MFMA GEMM (round-3 exact structure: single-buffer LDS, two barriers/K-step,
// no setprio).  out = A @ (Wh+Wl)^T + bias.  BM=128, BN=64, BK=32, 4 waves.
// LDS XOR-swizzle: 16B chunk pos ^= (row>>1)&3.
// AF32: A is f32, converted to bf16 in-register during staging (same RNE bits
//       the old convert kernel produced).
// MODE 0: f32 flat [M,N]
// MODE 1: bf16 [B,H,T,DK]            (Q: row-major per head)
// MODE 3: bf16 K fragment-major      [bh][kt][c*2+khi][l31][8]
// MODE 4: bf16 V fragment-major      [bh][kt][(kgrp*2+dblk)*2+khi][l31][8]
// ---------------------------------------------------------------------------
template<int MODE, bool AF32>
__device__ inline void gemm_body(
    const void* __restrict__ Av, const unsigned short* __restrict__ Bh,
    const unsigned short* __restrict__ Bl, const float* __restrict__ bias,
    unsigned short* __restrict__ outb, float* __restrict__ outf)
{
    __shared__ unsigned short As[128 * 32];
    __shared__ unsigned short Bsh[64 * 32];
    __shared__ unsigned short Bsl[64 * 32];

    const int tid = threadIdx.x;
    const int m0 = blockIdx.y * 128, n0 = blockIdx.x * 64;
    const int lane31 = tid & 31, hi8 = (tid & 63) >> 5;
    const int wv = tid >> 6, wm = wv >> 1, wn = wv & 1;

    f32x16 acc0 = {}, acc1 = {};

    for (int kb = 0; kb < 16; ++kb) {
        const int k0 = kb * 32;
        // ---- stage A (2 chunks/thread) and B (1 chunk/thread), swizzled
#pragma unroll
        for (int i = 0; i < 2; ++i) {
            const int c = tid + i * 256;          // 512 chunks: 128 rows x 4
            const int r = c >> 2, pos = c & 3;
            const int sw = pos ^ ((r >> 1) & 3);
            short8v av;
            if constexpr (AF32) {
                const float* Af = (const float*)Av;
                const float4 f0 = *(const float4*)&Af[(size_t)(m0 + r) * DIN + k0 + pos * 8];
                const float4 f1 = *(const float4*)&Af[(size_t)(m0 + r) * DIN + k0 + pos * 8 + 4];
                union { unsigned w[4]; short8v v; } u;
                u.w[0] = pk2(f0.x, f0.y); u.w[1] = pk2(f0.z, f0.w);
                u.w[2] = pk2(f1.x, f1.y); u.w[3] = pk2(f1.z, f1.w);
                av = u.v;
            } else {
                const unsigned short* Ab = (const unsigned short*)Av;
                av = *(const short8v*)&Ab[(size_t)(m0 + r) * DIN + k0 + pos * 8];
            }
            *(short8v*)((char*)As + r * 64 + sw * 16) = av;
        }
        {
            const int c = tid;                    // 256 chunks: 64 rows x 4
            const int r = c >> 2, pos = c & 3;
            const short8v bh = *(const short8v*)&Bh[(size_t)(n0 + r) * DIN + k0 + pos * 8];
            const short8v bl = *(const short8v*)&Bl[(size_t)(n0 + r) * DIN + k0 + pos * 8];
            const int sw = pos ^ ((r >> 1) & 3);
            *(short8v*)((char*)Bsh + r * 64 + sw * 16) = bh;
            *(short8v*)((char*)Bsl + r * 64 + sw * 16) = bl;
        }
        __syncthreads();
        // ---- compute 2 k-steps of 16
#pragma unroll
        for (int ks = 0; ks < 2; ++ks) {
            const int pos = ks * 2 + hi8;
            short8v a0, a1, bhf, blf;
            { const int r = wm * 64 + lane31;
              a0 = *(const short8v*)((char*)As + r * 64 + ((pos ^ ((r >> 1) & 3)) << 4)); }
            { const int r = wm * 64 + 32 + lane31;
              a1 = *(const short8v*)((char*)As + r * 64 + ((pos ^ ((r >> 1) & 3)) << 4)); }
            { const int r = wn * 32 + lane31;
              bhf = *(const short8v*)((char*)Bsh + r * 64 + ((pos ^ ((r >> 1) & 3)) << 4));
              blf = *(const short8v*)((char*)Bsl + r * 64 + ((pos ^ ((r >> 1) & 3)) << 4)); }
            acc0 = mfma3216(a0, bhf, acc0);
            acc0 = mfma3216(a0, blf, acc0);
            acc1 = mfma3216(a1, bhf, acc1);
            acc1 = mfma3216(a1, blf, acc1);
        }
        __syncthreads();
    }

    // ---- epilogue
    const int n = n0 + wn * 32 + lane31;
    const float bn = bias[n];
#pragma unroll
    for (int r = 0; r < 16; ++r) {
        const int row = (r & 3) + 8 * (r >> 2) + 4 * hi8;
#pragma unroll
        for (int mt = 0; mt < 2; ++mt) {
            const int m = m0 + wm * 64 + mt * 32 + row;
            const float v = (mt ? acc1[r] : acc0[r]) + bn;
            if (MODE == 0) {
                outf[(size_t)m * DOUT + n] = v;
            } else {
                const int bb = m >> 11, t = m & (T_ - 1);
                const int hh = n >> 6,  d = n & (DK_ - 1);
                const size_t bh = (size_t)bb * H_ + hh;
                if (MODE == 1) {
                    outb[(bh * T_ + t) * DK_ + d] = bf16c(v);
                } else if (MODE == 3) {
                    // K-frag: [bh][kt][c*2+khi][l31][8]
                    const int kt = t >> 5, l31 = t & 31;
                    const int c = d >> 4, khi = (d >> 3) & 1, e = d & 7;
                    outb[(bh * 64 + kt) * 2048 + (c * 2 + khi) * 256 + l31 * 8 + e] = bf16c(v);
                } else {
                    // V-frag: [bh][kt][(kgrp*2+dblk)*2+khi][l31][8]
                    const int kt = t >> 5, kgrp = (t >> 4) & 1, khi = (t >> 3) & 1, e = t & 7;
                    const int dblk = d >> 5, l31 = d & 31;
                    outb[(bh * 64 + kt) * 2048 + ((kgrp * 2 + dblk) * 2 + khi) * 256 + l31 * 8 + e] = bf16c(v);
                }
            }
        }
    }
}

__global__ __launch_bounds__(256) void qkv_gemm(
    const float* __restrict__ q, const float* __restrict__ k, const float* __restrict__ v,
    const unsigned short* __restrict__ Wh, const unsigned short* __restrict__ Wl,
    const float* __restrict__ bq, const float* __restrict__ bk, const float* __restrict__ bv,
    unsigned short* __restrict__ Qh, unsigned short* __restrict__ Kf,
    unsigned short* __restrict__ Vf)
{
    const int z = blockIdx.z;
    if (z == 0)      gemm_body<1, true>(q, Wh,          Wl,          bq, Qh, nullptr);
    else if (z == 1) gemm_body<3, true>(k, Wh + 262144, Wl + 262144, bk, Kf, nullptr);
    else             gemm_body<4, true>(v, Wh + 524288, Wl + 524288, bv, Vf, nullptr);
}

__global__ __launch_bounds__(256) void out_gemm(
    const unsigned short* __restrict__ A,
    const unsigned short* __restrict__ Bh, const unsigned short* __restrict__ Bl,
    const float* __restrict__ bias, float* __restrict__ out)
{
    gemm_body<0, false>(A, Bh, Bl, bias, nullptr, out);
}

// ---------------------------------------------------------------------------
// MFMA two-pass attention — round-3 exact compute structure (same values,
// same MFMA/accumulation order). Only change: K/V fragment-major layout so
// every load is a contiguous, fully-coalesced 1KB wave-load (kills the 4x
// L2 over-fetch of the strided per-lane pattern).
// Block = 4 waves, 32 q-rows of one (b,h); each wave a 512-key quarter.
// ---------------------------------------------------------------------------
__global__ __launch_bounds__(256) void attn_kernel(
    const unsigned short* __restrict__ Qh, const unsigned short* __restrict__ Kf,
    const unsigned short* __restrict__ Vf, unsigned short* __restrict__ concat)
{
    __shared__ float lds_l[4][32];
    __shared__ float lds_out[3][32][64];

    const int bid = blockIdx.x;
    const int xcd = bid & 7;
    const int j   = bid >> 3;
    const int bh  = 2 * xcd + (j >> 6);
    const int qt  = j & 63;

    const int tid    = threadIdx.x;
    const int w      = tid >> 6;
    const int l      = tid & 63;
    const int lane31 = l & 31;
    const int hi     = l >> 5;

    const int q0 = qt * 32;
    const unsigned short* Qb = Qh + ((size_t)bh * T_ + q0) * DK_;

    // Q B-fragments: col = lane31 (query), k = d = c*16 + hi*8 + {0..7}
    short8v qf[4];
#pragma unroll
    for (int c = 0; c < 4; ++c)
        qf[c] = *(const short8v*)(Qb + (size_t)lane31 * DK_ + c * 16 + hi * 8);

    // fragment-major bases for this wave's 16 tiles (keys w*512 .. w*512+511)
    const unsigned short* Kw = Kf + ((size_t)bh * 64 + w * 16) * 2048 + hi * 256 + lane31 * 8;
    const unsigned short* Vw = Vf + ((size_t)bh * 64 + w * 16) * 2048 + hi * 256 + lane31 * 8;

    // ---- pass 1: denominators (round-3 serial accumulation order)
    float lsum = 0.f;
    for (int kt = 0; kt < 16; ++kt) {
        const unsigned short* Kt = Kw + kt * 2048;
        short8v kf[4];
#pragma unroll
        for (int c = 0; c < 4; ++c)
            kf[c] = *(const short8v*)(Kt + c * 512);
        f32x16 acc = {};
#pragma unroll
        for (int c = 0; c < 4; ++c)
            acc = mfma3216(kf[c], qf[c], acc);
#pragma unroll
        for (int r = 0; r < 16; ++r)
            lsum += __expf(acc[r]);
    }
    lsum += __shfl_xor(lsum, 32);
    if (l < 32) lds_l[w][l] = lsum;
    __syncthreads();
    const float ltot = lds_l[0][lane31] + lds_l[1][lane31]
                     + lds_l[2][lane31] + lds_l[3][lane31];
    const float thr = ltot * (1.0f / 2048.0f);   // e > thr  <=>  p > row mean (=1/T)
    const float inv = 1.0f / ltot;

    // ---- pass 2: masked PV (round-3 repack and MFMA order)
    f32x16 o0 = {}, o1 = {};
    for (int kt = 0; kt < 16; ++kt) {
        const unsigned short* Kt = Kw + kt * 2048;
        short8v kf[4];
#pragma unroll
        for (int c = 0; c < 4; ++c)
            kf[c] = *(const short8v*)(Kt + c * 512);
        f32x16 acc = {};
#pragma unroll
        for (int c = 0; c < 4; ++c)
            acc = mfma3216(kf[c], qf[c], acc);

        float p[16];
#pragma unroll
        for (int r = 0; r < 16; ++r) {
            const float e = __expf(acc[r]);
            p[r] = (e > thr) ? e : 0.f;
        }

        // repack S^T (key split {0-3,8-11,..}+4hi) -> PV A-frag (keys 8hi..8hi+7)
        short8v pa[2];
#pragma unroll
        for (int h = 0; h < 2; ++h) {
            const unsigned a  = pk2(p[8 * h + 0], p[8 * h + 1]);
            const unsigned b2 = pk2(p[8 * h + 2], p[8 * h + 3]);
            const unsigned c2 = pk2(p[8 * h + 4], p[8 * h + 5]);
            const unsigned d2 = pk2(p[8 * h + 6], p[8 * h + 7]);
            const unsigned sa = (unsigned)__shfl_xor((int)a,  32);
            const unsigned sb = (unsigned)__shfl_xor((int)b2, 32);
            const unsigned sc = (unsigned)__shfl_xor((int)c2, 32);
            const unsigned sd = (unsigned)__shfl_xor((int)d2, 32);
            union { unsigned w2[4]; short8v v8; } u;
            u.w2[0] = hi ? sc : a;
            u.w2[1] = hi ? sd : b2;
            u.w2[2] = hi ? c2 : sa;
            u.w2[3] = hi ? d2 : sb;
            pa[h] = u.v8;
        }

        const unsigned short* Vt_ = Vw + kt * 2048;
#pragma unroll
        for (int h = 0; h < 2; ++h) {
            short8v vf0 = *(const short8v*)(Vt_ + (2 * h)     * 512);
            short8v vf1 = *(const short8v*)(Vt_ + (2 * h + 1) * 512);
            o0 = mfma3216(pa[h], vf0, o0);
            o1 = mfma3216(pa[h], vf1, o1);
        }
    }

    // ---- combine 4 key-quarters via LDS, scale by 1/l, store bf16
    if (w) {
#pragma unroll
        for (int r = 0; r < 16; ++r) {
            const int row = (r & 3) + 8 * (r >> 2) + 4 * hi;
            lds_out[w - 1][row][lane31]      = o0[r];
            lds_out[w - 1][row][32 + lane31] = o1[r];
        }
    }
    __syncthreads();
    if (!w) {
        const int b = bh >> 3, h = bh & 7;
        unsigned short* Cb = concat + ((size_t)b * T_ + q0) * DOUT + h * DK_;
#pragma unroll
        for (int r = 0; r < 16; ++r) {
            const int row = (r & 3) + 8 * (r >> 2) + 4 * hi;
            const float iv = __shfl(inv, row);
            const float v0 = o0[r] + lds_out[0][row][lane31]
                           + lds_out[1][row][lane31] + lds_out[2][row][lane31];
            const float v1 = o1[r] + lds_out[0][row][32 + lane31]
                           + lds_out[1][row][32 + lane31] + lds_out[2][row][32 + lane31];
            Cb[(size_t)row * DOUT + lane31]      = bf16c(v0 * iv);
            Cb[(size_t)row * DOUT + 32 + lane31] = bf16c(v1 * iv);
        }
    }
}

// ---------------------------------------------------------------------------
extern "C" void kernel_launch(void* const* d_in, const int* in_sizes, int n_in,
                              void* d_out, int out_size, void* d_ws, size_t ws_size,
                              hipStream_t stream)
{
    const float* q  = (const float*)d_in[0];
    const float* k  = (const float*)d_in[1];
    const float* v  = (const float*)d_in[2];
    const float* Wq = (const float*)d_in[3];
    const float* bq = (const float*)d_in[4];
    const float* Wk = (const float*)d_in[5];
    const float* bk = (const float*)d_in[6];
    const float* Wv = (const float*)d_in[7];
    const float* bv = (const float*)d_in[8];
    const float* Wo = (const float*)d_in[9];
    const float* bo = (const float*)d_in[10];
    float* out = (float*)d_out;

    constexpr size_t M2 = 2097152;  // 2M elements
    unsigned short* ws     = (unsigned short*)d_ws;
    unsigned short* Qh     = ws;
    unsigned short* Kf     = ws + 1 * M2;
    unsigned short* Vf     = ws + 2 * M2;
    unsigned short* concat = ws + 3 * M2;
    unsigned short* Wh     = ws + 4 * M2;        // 4 x 256K
    unsigned short* Wl     = ws + 4 * M2 + 1048576;

    wconvert_kernel<<<256, 256, 0, stream>>>(Wq, Wk, Wv, Wo, Wh, Wl);
    qkv_gemm<<<dim3(8, 32, 3), 256, 0, stream>>>(q, k, v, Wh, Wl, bq, bk, bv, Qh, Kf, Vf);
    attn_kernel<<<dim3(1024), 256, 0, stream>>>(Qh, Kf, Vf, concat);
    out_gemm<<<dim3(8, 32), 256, 0, stream>>>(concat, Wh + 786432, Wl + 786432, bo, out);
}

// Round 9
// 92.634 us; speedup vs baseline: 31.9457x; 1.1166x over previous
//
#include <hip/hip_runtime.h>

// B=2, T=2048, D_IN=D_OUT=512, H=8, DK=64
constexpr int B_   = 2;
constexpr int T_   = 2048;
constexpr int DIN  = 512;
constexpr int DOUT = 512;
constexpr int H_   = 8;
constexpr int DK_  = 64;

typedef float    f32x16  __attribute__((ext_vector_type(16)));
typedef short    short8v __attribute__((ext_vector_type(8)));
typedef __bf16   bf16x8  __attribute__((ext_vector_type(8)));

__device__ inline f32x16 mfma3216(short8v a, short8v b, f32x16 c) {
    return __builtin_amdgcn_mfma_f32_32x32x16_bf16(
        __builtin_bit_cast(bf16x8, a), __builtin_bit_cast(bf16x8, b), c, 0, 0, 0);
}

__device__ inline unsigned short bf16c(float f) {
    return __builtin_bit_cast(unsigned short, (__bf16)f);
}
__device__ inline float bf2f(unsigned short u) {
    return (float)__builtin_bit_cast(__bf16, u);
}
__device__ inline unsigned pk2(float lo, float hi) {
    return (unsigned)bf16c(lo) | ((unsigned)bf16c(hi) << 16);
}

// ---------------------------------------------------------------------------
// Weight conversion only: Wq,Wk,Wv,Wo f32 -> bf16 hi + bf16 lo. 256 blocks.
// (r6 verbatim)
// ---------------------------------------------------------------------------
__global__ __launch_bounds__(256) void wconvert_kernel(
    const float* __restrict__ Wq, const float* __restrict__ Wk,
    const float* __restrict__ Wv, const float* __restrict__ Wo,
    unsigned short* __restrict__ Wh, unsigned short* __restrict__ Wl)
{
    const int b = blockIdx.x, t = threadIdx.x;
    const int wi = b >> 6;
    const float* src = wi == 0 ? Wq : (wi == 1 ? Wk : (wi == 2 ? Wv : Wo));
    unsigned short* hi = Wh + (size_t)wi * 262144;
    unsigned short* lo = Wl + (size_t)wi * 262144;
    const size_t off = (size_t)(b & 63) * 4096;
#pragma unroll
    for (int c = 0; c < 4; ++c) {
        const size_t idx = off + (size_t)c * 1024 + (size_t)t * 4;
        const float4 x = *(const float4*)&src[idx];
        ushort4 h;
        h.x = bf16c(x.x); h.y = bf16c(x.y); h.z = bf16c(x.z); h.w = bf16c(x.w);
        *(ushort4*)&hi[idx] = h;
        ushort4 l2;
        l2.x = bf16c(x.x - bf2f(h.x));
        l2.y = bf16c(x.y - bf2f(h.y));
        l2.z = bf16c(x.z - bf2f(h.z));
        l2.w = bf16c(x.w - bf2f(h.w));
        *(ushort4*)&lo[idx] = l2;
    }
}

// ---------------------------------------------------------------------------
// Epilogue store: MODE 0 f32 [M,N]; 1 bf16 [B,H,T,DK]; 3 K-frag; 4 V-frag.
// ---------------------------------------------------------------------------
template<int MODE>
__device__ __forceinline__ void store_c(unsigned short* __restrict__ outb,
                                        float* __restrict__ outf,
                                        int m, int n, float v)
{
    if constexpr (MODE == 0) {
        outf[(size_t)m * DOUT + n] = v;
    } else {
        const int bb = m >> 11, t = m & (T_ - 1);
        const int hh = n >> 6,  d = n & (DK_ - 1);
        const size_t bh = (size_t)bb * H_ + hh;
        if constexpr (MODE == 1) {
            outb[(bh * T_ + t) * DK_ + d] = bf16c(v);
        } else if constexpr (MODE == 3) {
            // K-frag: [bh][kt][c*2+khi][l31][8]
            const int kt = t >> 5, l31 = t & 31;
            const int c = d >> 4, khi = (d >> 3) & 1, e = d & 7;
            outb[(bh * 64 + kt) * 2048 + (c * 2 + khi) * 256 + l31 * 8 + e] = bf16c(v);
        } else {
            // V-frag: [bh][kt][(kgrp*2+dblk)*2+khi][l31][8]
            const int kt = t >> 5, kgrp = (t >> 4) & 1, khi = (t >> 3) & 1, e = t & 7;
            const int dblk = d >> 5, l31 = d & 31;
            outb[(bh * 64 + kt) * 2048 + ((kgrp * 2 + dblk) * 2 + khi) * 256 + l31 * 8 + e] = bf16c(v);
        }
    }
}

// ---------------------------------------------------------------------------
// MFMA GEMM (r7 form — exonerated bit-neutral by the r7/r8 identity):
// out = A @ (Wh+Wl)^T + bias.  BM=128, BN=64 or 128, BK=32, 4 waves.
// Single LDS buffer, two barriers per K-step, reg-prefetch of step kb+1
// issued between stage-barrier and compute.
// LDS XOR-swizzle: 16B chunk pos ^= (row>>1)&3.
// ---------------------------------------------------------------------------
template<int MODE, bool AF32, int BN>
__device__ inline void gemm_body(
    const void* __restrict__ Av, const unsigned short* __restrict__ Bhp,
    const unsigned short* __restrict__ Blp, const float* __restrict__ bias,
    unsigned short* __restrict__ outb, float* __restrict__ outf)
{
    __shared__ unsigned short As[128 * 32];
    __shared__ unsigned short Bsh[BN * 32];
    __shared__ unsigned short Bsl[BN * 32];

    const int tid = threadIdx.x;
    const int m0 = blockIdx.y * 128, n0 = blockIdx.x * BN;
    const int lane31 = tid & 31, hi8 = (tid & 63) >> 5;
    const int wv = tid >> 6, wm = wv >> 1, wn = wv & 1;

    const int r_  = tid >> 2, pos_ = tid & 3;
    const int r2_ = r_ + 64;
    const int sw_  = pos_ ^ ((r_  >> 1) & 3);
    const int sw2_ = pos_ ^ ((r2_ >> 1) & 3);

    short8v a0r, a1r, bh0r, bl0r, bh1r, bl1r;

    auto gload = [&](int kb) {
        const int k0 = kb * 32;
        if constexpr (AF32) {
            const float* Af = (const float*)Av;
            {
                const float4 f0 = *(const float4*)&Af[(size_t)(m0 + r_) * DIN + k0 + pos_ * 8];
                const float4 f1 = *(const float4*)&Af[(size_t)(m0 + r_) * DIN + k0 + pos_ * 8 + 4];
                union { unsigned w[4]; short8v v; } u;
                u.w[0] = pk2(f0.x, f0.y); u.w[1] = pk2(f0.z, f0.w);
                u.w[2] = pk2(f1.x, f1.y); u.w[3] = pk2(f1.z, f1.w);
                a0r = u.v;
            }
            {
                const float4 f0 = *(const float4*)&Af[(size_t)(m0 + r2_) * DIN + k0 + pos_ * 8];
                const float4 f1 = *(const float4*)&Af[(size_t)(m0 + r2_) * DIN + k0 + pos_ * 8 + 4];
                union { unsigned w[4]; short8v v; } u;
                u.w[0] = pk2(f0.x, f0.y); u.w[1] = pk2(f0.z, f0.w);
                u.w[2] = pk2(f1.x, f1.y); u.w[3] = pk2(f1.z, f1.w);
                a1r = u.v;
            }
        } else {
            const unsigned short* Ab = (const unsigned short*)Av;
            a0r = *(const short8v*)&Ab[(size_t)(m0 + r_)  * DIN + k0 + pos_ * 8];
            a1r = *(const short8v*)&Ab[(size_t)(m0 + r2_) * DIN + k0 + pos_ * 8];
        }
        bh0r = *(const short8v*)&Bhp[(size_t)(n0 + r_) * DIN + k0 + pos_ * 8];
        bl0r = *(const short8v*)&Blp[(size_t)(n0 + r_) * DIN + k0 + pos_ * 8];
        if constexpr (BN == 128) {
            bh1r = *(const short8v*)&Bhp[(size_t)(n0 + r2_) * DIN + k0 + pos_ * 8];
            bl1r = *(const short8v*)&Blp[(size_t)(n0 + r2_) * DIN + k0 + pos_ * 8];
        }
    };
    auto swrite = [&]() {
        *(short8v*)((char*)As + r_  * 64 + sw_  * 16) = a0r;
        *(short8v*)((char*)As + r2_ * 64 + sw2_ * 16) = a1r;
        *(short8v*)((char*)Bsh + r_ * 64 + sw_ * 16) = bh0r;
        *(short8v*)((char*)Bsl + r_ * 64 + sw_ * 16) = bl0r;
        if constexpr (BN == 128) {
            *(short8v*)((char*)Bsh + r2_ * 64 + sw2_ * 16) = bh1r;
            *(short8v*)((char*)Bsl + r2_ * 64 + sw2_ * 16) = bl1r;
        }
    };

    f32x16 acc00 = {}, acc01 = {}, acc10 = {}, acc11 = {};

    gload(0);
    for (int kb = 0; kb < 16; ++kb) {
        swrite();
        __syncthreads();
        if (kb < 15) gload(kb + 1);       // prefetch next step during compute
#pragma unroll
        for (int ks = 0; ks < 2; ++ks) {
            const int pos = ks * 2 + hi8;
            short8v a0, a1;
            { const int r = wm * 64 + lane31;
              a0 = *(const short8v*)((char*)As + r * 64 + ((pos ^ ((r >> 1) & 3)) << 4)); }
            { const int r = wm * 64 + 32 + lane31;
              a1 = *(const short8v*)((char*)As + r * 64 + ((pos ^ ((r >> 1) & 3)) << 4)); }
            if constexpr (BN == 64) {
                short8v b0h, b0l;
                { const int r = wn * 32 + lane31;
                  b0h = *(const short8v*)((char*)Bsh + r * 64 + ((pos ^ ((r >> 1) & 3)) << 4));
                  b0l = *(const short8v*)((char*)Bsl + r * 64 + ((pos ^ ((r >> 1) & 3)) << 4)); }
                acc00 = mfma3216(a0, b0h, acc00);
                acc00 = mfma3216(a0, b0l, acc00);
                acc10 = mfma3216(a1, b0h, acc10);
                acc10 = mfma3216(a1, b0l, acc10);
            } else {
                short8v b0h, b0l, b1h, b1l;
                { const int r = wn * 64 + lane31;
                  b0h = *(const short8v*)((char*)Bsh + r * 64 + ((pos ^ ((r >> 1) & 3)) << 4));
                  b0l = *(const short8v*)((char*)Bsl + r * 64 + ((pos ^ ((r >> 1) & 3)) << 4)); }
                { const int r = wn * 64 + 32 + lane31;
                  b1h = *(const short8v*)((char*)Bsh + r * 64 + ((pos ^ ((r >> 1) & 3)) << 4));
                  b1l = *(const short8v*)((char*)Bsl + r * 64 + ((pos ^ ((r >> 1) & 3)) << 4)); }
                acc00 = mfma3216(a0, b0h, acc00);
                acc00 = mfma3216(a0, b0l, acc00);
                acc01 = mfma3216(a0, b1h, acc01);
                acc01 = mfma3216(a0, b1l, acc01);
                acc10 = mfma3216(a1, b0h, acc10);
                acc10 = mfma3216(a1, b0l, acc10);
                acc11 = mfma3216(a1, b1h, acc11);
                acc11 = mfma3216(a1, b1l, acc11);
            }
        }
        __syncthreads();
    }

    // ---- epilogue
    const int nb = n0 + wn * (BN / 2) + lane31;
#pragma unroll
    for (int r = 0; r < 16; ++r) {
        const int row = (r & 3) + 8 * (r >> 2) + 4 * hi8;
        store_c<MODE>(outb, outf, m0 + wm * 64 + row,      nb, acc00[r] + bias[nb]);
        store_c<MODE>(outb, outf, m0 + wm * 64 + 32 + row, nb, acc10[r] + bias[nb]);
        if constexpr (BN == 128) {
            store_c<MODE>(outb, outf, m0 + wm * 64 + row,      nb + 32, acc01[r] + bias[nb + 32]);
            store_c<MODE>(outb, outf, m0 + wm * 64 + 32 + row, nb + 32, acc11[r] + bias[nb + 32]);
        }
    }
}

__global__ __launch_bounds__(256) void qkv_gemm(
    const float* __restrict__ q, const float* __restrict__ k, const float* __restrict__ v,
    const unsigned short* __restrict__ Wh, const unsigned short* __restrict__ Wl,
    const float* __restrict__ bq, const float* __restrict__ bk, const float* __restrict__ bv,
    unsigned short* __restrict__ Qh, unsigned short* __restrict__ Kf,
    unsigned short* __restrict__ Vf)
{
    const int z = blockIdx.z;
    if (z == 0)      gemm_body<1, true, 128>(q, Wh,          Wl,          bq, Qh, nullptr);
    else if (z == 1) gemm_body<3, true, 128>(k, Wh + 262144, Wl + 262144, bk, Kf, nullptr);
    else             gemm_body<4, true, 128>(v, Wh + 524288, Wl + 524288, bv, Vf, nullptr);
}

__global__ __launch_bounds__(256) void out_gemm(
    const unsigned short* __restrict__ A,
    const unsigned short* __restrict__ Bh, const unsigned short* __restrict__ Bl,
    const float* __restrict__ bias, float* __restrict__ out)
{
    gemm_body<0, false, 64>(A, Bh, Bl, bias, nullptr, out);
}

// ---------------------------------------------------------------------------
// MFMA two-pass attention — r6 VERBATIM (the passing version). Fragment-major
// K/V, straight 16-tile loops, NO register ping-pong (that class is convicted
// by the r8 isolation experiment and permanently abandoned).
// Block = 4 waves, 32 q-rows of one (b,h); each wave a 512-key quarter.
// ---------------------------------------------------------------------------
__global__ __launch_bounds__(256) void attn_kernel(
    const unsigned short* __restrict__ Qh, const unsigned short* __restrict__ Kf,
    const unsigned short* __restrict__ Vf, unsigned short* __restrict__ concat)
{
    __shared__ float lds_l[4][32];
    __shared__ float lds_out[3][32][64];

    const int bid = blockIdx.x;
    const int xcd = bid & 7;
    const int j   = bid >> 3;
    const int bh  = 2 * xcd + (j >> 6);
    const int qt  = j & 63;

    const int tid    = threadIdx.x;
    const int w      = tid >> 6;
    const int l      = tid & 63;
    const int lane31 = l & 31;
    const int hi     = l >> 5;

    const int q0 = qt * 32;
    const unsigned short* Qb = Qh + ((size_t)bh * T_ + q0) * DK_;

    // Q B-fragments: col = lane31 (query), k = d = c*16 + hi*8 + {0..7}
    short8v qf[4];
#pragma unroll
    for (int c = 0; c < 4; ++c)
        qf[c] = *(const short8v*)(Qb + (size_t)lane31 * DK_ + c * 16 + hi * 8);

    // fragment-major bases for this wave's 16 tiles (keys w*512 .. w*512+511)
    const unsigned short* Kw = Kf + ((size_t)bh * 64 + w * 16) * 2048 + hi * 256 + lane31 * 8;
    const unsigned short* Vw = Vf + ((size_t)bh * 64 + w * 16) * 2048 + hi * 256 + lane31 * 8;

    // ---- pass 1: denominators
    float lsum = 0.f;
    for (int kt = 0; kt < 16; ++kt) {
        const unsigned short* Kt = Kw + kt * 2048;
        short8v kf[4];
#pragma unroll
        for (int c = 0; c < 4; ++c)
            kf[c] = *(const short8v*)(Kt + c * 512);
        f32x16 acc = {};
#pragma unroll
        for (int c = 0; c < 4; ++c)
            acc = mfma3216(kf[c], qf[c], acc);
#pragma unroll
        for (int r = 0; r < 16; ++r)
            lsum += __expf(acc[r]);
    }
    lsum += __shfl_xor(lsum, 32);
    if (l < 32) lds_l[w][l] = lsum;
    __syncthreads();
    const float ltot = lds_l[0][lane31] + lds_l[1][lane31]
                     + lds_l[2][lane31] + lds_l[3][lane31];
    const float thr = ltot * (1.0f / 2048.0f);   // e > thr  <=>  p > row mean (=1/T)
    const float inv = 1.0f / ltot;

    // ---- pass 2: masked PV
    f32x16 o0 = {}, o1 = {};
    for (int kt = 0; kt < 16; ++kt) {
        const unsigned short* Kt = Kw + kt * 2048;
        short8v kf[4];
#pragma unroll
        for (int c = 0; c < 4; ++c)
            kf[c] = *(const short8v*)(Kt + c * 512);
        f32x16 acc = {};
#pragma unroll
        for (int c = 0; c < 4; ++c)
            acc = mfma3216(kf[c], qf[c], acc);

        float p[16];
#pragma unroll
        for (int r = 0; r < 16; ++r) {
            const float e = __expf(acc[r]);
            p[r] = (e > thr) ? e : 0.f;
        }

        // repack S^T (key split {0-3,8-11,..}+4hi) -> PV A-frag (keys 8hi..8hi+7)
        short8v pa[2];
#pragma unroll
        for (int h = 0; h < 2; ++h) {
            const unsigned a  = pk2(p[8 * h + 0], p[8 * h + 1]);
            const unsigned b2 = pk2(p[8 * h + 2], p[8 * h + 3]);
            const unsigned c2 = pk2(p[8 * h + 4], p[8 * h + 5]);
            const unsigned d2 = pk2(p[8 * h + 6], p[8 * h + 7]);
            const unsigned sa = (unsigned)__shfl_xor((int)a,  32);
            const unsigned sb = (unsigned)__shfl_xor((int)b2, 32);
            const unsigned sc = (unsigned)__shfl_xor((int)c2, 32);
            const unsigned sd = (unsigned)__shfl_xor((int)d2, 32);
            union { unsigned w2[4]; short8v v8; } u;
            u.w2[0] = hi ? sc : a;
            u.w2[1] = hi ? sd : b2;
            u.w2[2] = hi ? c2 : sa;
            u.w2[3] = hi ? d2 : sb;
            pa[h] = u.v8;
        }

        const unsigned short* Vt_ = Vw + kt * 2048;
#pragma unroll
        for (int h = 0; h < 2; ++h) {
            short8v vf0 = *(const short8v*)(Vt_ + (2 * h)     * 512);
            short8v vf1 = *(const short8v*)(Vt_ + (2 * h + 1) * 512);
            o0 = mfma3216(pa[h], vf0, o0);
            o1 = mfma3216(pa[h], vf1, o1);
        }
    }

    // ---- combine 4 key-quarters via LDS, scale by 1/l, store bf16
    if (w) {
#pragma unroll
        for (int r = 0; r < 16; ++r) {
            const int row = (r & 3) + 8 * (r >> 2) + 4 * hi;
            lds_out[w - 1][row][lane31]      = o0[r];
            lds_out[w - 1][row][32 + lane31] = o1[r];
        }
    }
    __syncthreads();
    if (!w) {
        const int b = bh >> 3, h = bh & 7;
        unsigned short* Cb = concat + ((size_t)b * T_ + q0) * DOUT + h * DK_;
#pragma unroll
        for (int r = 0; r < 16; ++r) {
            const int row = (r & 3) + 8 * (r >> 2) + 4 * hi;
            const float iv = __shfl(inv, row);
            const float v0 = o0[r] + lds_out[0][row][lane31]
                           + lds_out[1][row][lane31] + lds_out[2][row][lane31];
            const float v1 = o1[r] + lds_out[0][row][32 + lane31]
                           + lds_out[1][row][32 + lane31] + lds_out[2][row][32 + lane31];
            Cb[(size_t)row * DOUT + lane31]      = bf16c(v0 * iv);
            Cb[(size_t)row * DOUT + 32 + lane31] = bf16c(v1 * iv);
        }
    }
}

// ---------------------------------------------------------------------------
extern "C" void kernel_launch(void* const* d_in, const int* in_sizes, int n_in,
                              void* d_out, int out_size, void* d_ws, size_t ws_size,
                              hipStream_t stream)
{
    const float* q  = (const float*)d_in[0];
    const float* k  = (const float*)d_in[1];
    const float* v  = (const float*)d_in[2];
    const float* Wq = (const float*)d_in[3];
    const float* bq = (const float*)d_in[4];
    const float* Wk = (const float*)d_in[5];
    const float* bk = (const float*)d_in[6];
    const float* Wv = (const float*)d_in[7];
    const float* bv = (const float*)d_in[8];
    const float* Wo = (const float*)d_in[9];
    const float* bo = (const float*)d_in[10];
    float* out = (float*)d_out;

    constexpr size_t M2 = 2097152;  // 2M elements
    unsigned short* ws     = (unsigned short*)d_ws;
    unsigned short* Qh     = ws;
    unsigned short* Kf     = ws + 1 * M2;
    unsigned short* Vf     = ws + 2 * M2;
    unsigned short* concat = ws + 3 * M2;
    unsigned short* Wh     = ws + 4 * M2;        // 4 x 256K
    unsigned short* Wl     = ws + 4 * M2 + 1048576;

    wconvert_kernel<<<256, 256, 0, stream>>>(Wq, Wk, Wv, Wo, Wh, Wl);
    qkv_gemm<<<dim3(4, 32, 3), 256, 0, stream>>>(q, k, v, Wh, Wl, bq, bk, bv, Qh, Kf, Vf);
    attn_kernel<<<dim3(1024), 256, 0, stream>>>(Qh, Kf, Vf, concat);
    out_gemm<<<dim3(8, 32), 256, 0, stream>>>(concat, Wh + 786432, Wl + 786432, bo, out);
}